// Round 4
// baseline (380.942 us; speedup 1.0000x reference)
//
#include <hip/hip_runtime.h>

typedef unsigned short u16;
typedef u16 u16x4 __attribute__((ext_vector_type(4)));
typedef u16 u16x8 __attribute__((ext_vector_type(8)));
typedef __bf16 bf16;
typedef bf16 bf16x8 __attribute__((ext_vector_type(8)));
typedef float f32x2 __attribute__((ext_vector_type(2)));
typedef float f32x4 __attribute__((ext_vector_type(4)));

__device__ __forceinline__ float bf2f(u16 v) {
  union { unsigned u; float f; } x; x.u = ((unsigned)v) << 16; return x.f;
}
__device__ __forceinline__ u16 f2bf(float f) {
  union { float f; unsigned u; } x; x.f = f;
  unsigned u = x.u;
  u += 0x7fffu + ((u >> 16) & 1u);   // RNE
  return (u16)(u >> 16);
}

// async global->LDS, 16B per lane; LDS base wave-uniform, global source per-lane (m173)
#define GLDS16(g, l) __builtin_amdgcn_global_load_lds( \
    (const __attribute__((address_space(1))) unsigned int*)(const void*)(g), \
    (__attribute__((address_space(3))) unsigned int*)(void*)(l), 16, 0, 0)

// ---------------- prep: 4 weight transposes + query cvt + bias cvts (standalone again) ----
// grid 6732: [0,576) transpose4; [576,6720) query fp32->bf16; [6720,6732) bias converts
__global__ __launch_bounds__(256) void prep_k(
    const float* __restrict__ Wq, const float* __restrict__ Wk,
    const float* __restrict__ Wv, const float* __restrict__ Wout,
    const float* __restrict__ query,
    const float* __restrict__ b0, const float* __restrict__ b1,
    const float* __restrict__ b2, const float* __restrict__ b3,
    u16* __restrict__ WT, u16* __restrict__ q_bf, u16* __restrict__ dstB)
{
  __shared__ u16 T[64][72];
  const int blk = blockIdx.x;
  const int t = threadIdx.x;
  if (blk < 576) {
    const int bz = blk / 144, rr = blk % 144;
    const int r0 = (rr / 12) * 64, c0 = (rr % 12) * 64;
    const float* W = (bz == 0) ? Wq : (bz == 1) ? Wk : (bz == 2) ? Wv : Wout;
    u16* O = WT + (size_t)bz * 768 * 768;
    #pragma unroll
    for (int p = 0; p < 2; ++p) {
      int v = t + p * 256;
      int r = v / 8, c = (v % 8) * 8;
      f32x4 x0 = *(const f32x4*)&W[(size_t)(r0 + r) * 768 + c0 + c];
      f32x4 x1 = *(const f32x4*)&W[(size_t)(r0 + r) * 768 + c0 + c + 4];
      #pragma unroll
      for (int i = 0; i < 4; ++i) { T[r][c + i] = f2bf(x0[i]); T[r][c + 4 + i] = f2bf(x1[i]); }
    }
    __syncthreads();
    #pragma unroll
    for (int p = 0; p < 2; ++p) {
      int v = t + p * 256;
      int r = v / 8, c = (v % 8) * 8;
      u16x8 tv;
      #pragma unroll
      for (int i = 0; i < 8; ++i) tv[i] = T[c + i][r];
      *(u16x8*)&O[(size_t)(c0 + r) * 768 + r0 + c] = tv;
    }
  } else if (blk < 6720) {
    const size_t i = (size_t)(blk - 576) * 256 + t;   // 6144*256 slots, *8 = 12582912
    f32x4 a = *(const f32x4*)&query[i * 8];
    f32x4 b = *(const f32x4*)&query[i * 8 + 4];
    u16x8 w;
    #pragma unroll
    for (int j = 0; j < 4; ++j) { w[j] = f2bf(a[j]); w[4 + j] = f2bf(b[j]); }
    *(u16x8*)&q_bf[i * 8] = w;
  } else {
    const int i = (blk - 6720) * 256 + t;   // 12*256 = 3072
    if (i < 3072) {
      int s = i / 768, si = i % 768;
      const float* src = (s == 0) ? b0 : (s == 1) ? b1 : (s == 2) ? b2 : b3;
      dstB[i] = f2bf(src[si]);
    }
  }
}

// ---------------- downsample v4: barrier-free LDS-free VALU streaming ----------------
// C[m][n] = sum_s W[m][s] * X[s][n].  Pure streaming: X read once (100MB fp32),
// compute only 3.2 GFLOP -> VALU outer-product beats any MFMA staging pipeline here
// (3 prior MFMA variants all latency-bound at ~47us on the barrier/LDS chain).
// grid (3 n-tiles x 64 bp x 4 m-quarters), block 128 (2 waves):
//  - blockIdx.z makes the W row-range block-uniform -> scalar (SMEM) loads, L2-hot
//  - lane owns 2 n-columns (f32x2), acc[16] f32x2 -> v_pk_fma_f32
//  - explicit xa/xb double-buffer: 8 rows (4KB/wave) in flight while 256 FMAs run
//  - zero barriers, zero LDS: waves stream independently; tail peeled (no OOB)
//  - m-siblings are 192 apart in linear block id (=0 mod 8) -> same XCD -> X re-reads hit L2
__global__ __launch_bounds__(128) void ds_k(
    const float* __restrict__ W_kds, const float* __restrict__ W_vds,
    const float* __restrict__ key, const float* __restrict__ value,
    u16* __restrict__ key_ds)     // [2][32][64][768] bf16
{
  const int t = threadIdx.x;
  const int pair = blockIdx.y >> 5, b = blockIdx.y & 31;
  const float* src = (pair ? value : key) + (size_t)b * 512 * 768
                   + blockIdx.x * 256 + t * 2;
  const float* W32 = (pair ? W_vds : W_kds) + (size_t)blockIdx.z * 16 * 512;
  u16* dst = key_ds + (size_t)pair * 1572864 + (size_t)b * 49152
           + (size_t)blockIdx.z * 16 * 768 + blockIdx.x * 256 + t * 2;

  f32x2 acc[16] = {};
  f32x2 xa[8], xb[8];
  #pragma unroll
  for (int u = 0; u < 8; ++u) xa[u] = *(const f32x2*)&src[(size_t)u * 768];

  #pragma unroll 1
  for (int s0 = 0; s0 < 496; s0 += 16) {
    #pragma unroll
    for (int u = 0; u < 8; ++u) xb[u] = *(const f32x2*)&src[(size_t)(s0 + 8 + u) * 768];
    #pragma unroll
    for (int u = 0; u < 8; ++u) {
      #pragma unroll
      for (int m = 0; m < 16; ++m) acc[m] += xa[u] * W32[m * 512 + s0 + u];
    }
    #pragma unroll
    for (int u = 0; u < 8; ++u) xa[u] = *(const f32x2*)&src[(size_t)(s0 + 16 + u) * 768];
    #pragma unroll
    for (int u = 0; u < 8; ++u) {
      #pragma unroll
      for (int m = 0; m < 16; ++m) acc[m] += xb[u] * W32[m * 512 + s0 + 8 + u];
    }
  }
  // tail: xa holds rows 496..503
  #pragma unroll
  for (int u = 0; u < 8; ++u) xb[u] = *(const f32x2*)&src[(size_t)(504 + u) * 768];
  #pragma unroll
  for (int u = 0; u < 8; ++u) {
    #pragma unroll
    for (int m = 0; m < 16; ++m) acc[m] += xa[u] * W32[m * 512 + 496 + u];
  }
  #pragma unroll
  for (int u = 0; u < 8; ++u) {
    #pragma unroll
    for (int m = 0; m < 16; ++m) acc[m] += xb[u] * W32[m * 512 + 504 + u];
  }

  #pragma unroll
  for (int m = 0; m < 16; ++m) {
    union { u16 h[2]; unsigned w; } o;
    o.h[0] = f2bf(acc[m][0]); o.h[1] = f2bf(acc[m][1]);
    *(unsigned*)&dst[(size_t)m * 768] = o.w;
  }
}

// ---------------- fused phi_k/vals GEMM + KV-state ----------------
// grid 384 = (b,n). Per block: P = elu(key_ds[b]@WkT[n]+bk)+1, V = val_ds[b]@WvT[n]+bv
// (waves 0,2 = P rows; 1,3 = V rows), transposed to LDS, then sT[h][d] = P^T.. V
// in one 64x64x64 MFMA pass + z row-sums. Kills the phi_k/vals HBM round-trip.
__global__ __launch_bounds__(256) void fkv_k(
    const u16* __restrict__ key_ds,   // [2][32][64][768] bf16
    const u16* __restrict__ WT,       // WkT at +768^2, WvT at +2*768^2
    const u16* __restrict__ bias_c,   // bk at +768, bv at +1536
    u16* __restrict__ sT, float* __restrict__ z)
{
  __shared__ char sm[32768];
  u16* T0 = (u16*)sm;                 // 4 stage tiles [64][64] bf16, chunk-swizzled
  u16* Pt = (u16*)sm;                 // overlay after GEMM: [64][72]
  u16* Vt = (u16*)(sm + 9216);        // [64][72]
  const int x = blockIdx.x;           // b*12 + n
  const int b = x / 12, n = x % 12;
  const int t = threadIdx.x, wave = t >> 6, lane = t & 63;
  const u16* srcs[4] = {
    key_ds + (size_t)b * 49152,                       // A1 = key_ds[b]
    WT + 589824 + (size_t)n * 49152,                  // B1 = WkT rows n*64..
    key_ds + 1572864 + (size_t)b * 49152,             // A2 = val_ds[b]
    WT + 2 * 589824 + (size_t)n * 49152 };            // B2 = WvT rows n*64..
  const int grow = lane >> 3;                         // row in 8-row GLDS group
  const int gchunk = (lane & 7) ^ (grow & 7);         // source chunk swizzle
  const int isV = wave & 1;
  const int wm = (wave >> 1) * 32;                    // k-rows
  u16* Atile = T0 + (isV ? 2 : 0) * 4096;
  u16* Btile = T0 + (isV ? 3 : 1) * 4096;
  const int lrow = lane & 15, quad = lane >> 4;
  f32x4 acc[2][4] = {};

  for (int k0 = 0; k0 < 768; k0 += 64) {
    // stage: wave w loads tile w (8 GLDS x 1KB, 8 rows each, chunk-swizzled src)
    const u16* s = srcs[wave];
    u16* dtile = T0 + wave * 4096;
    #pragma unroll
    for (int j = 0; j < 8; ++j) {
      const u16* gsrc = s + (size_t)(j * 8 + grow) * 768 + k0 + gchunk * 8;
      GLDS16(gsrc, (char*)dtile + j * 1024);
    }
    __syncthreads();
    #pragma unroll
    for (int c = 0; c < 2; ++c) {
      bf16x8 av[2], bv[4];
      #pragma unroll
      for (int i = 0; i < 2; ++i) {
        const int row = wm + i * 16 + lrow;
        av[i] = *(const bf16x8*)&Atile[row * 64 + (((c * 4 + quad) ^ (row & 7)) * 8)];
      }
      #pragma unroll
      for (int j = 0; j < 4; ++j) {
        const int row = j * 16 + lrow;
        bv[j] = *(const bf16x8*)&Btile[row * 64 + (((c * 4 + quad) ^ (row & 7)) * 8)];
      }
      #pragma unroll
      for (int i = 0; i < 2; ++i)
        #pragma unroll
        for (int j = 0; j < 4; ++j)
          acc[i][j] = __builtin_amdgcn_mfma_f32_16x16x32_bf16(av[i], bv[j], acc[i][j], 0, 0, 0);
    }
    __syncthreads();
  }

  // epilogue: bias (+elu+1 for P), write TRANSPOSED tiles Pt[d][k], Vt[h][k]
  const u16* bias = bias_c + (isV ? 1536 : 768) + n * 64;
  u16* Ttile = isV ? Vt : Pt;
  #pragma unroll
  for (int i = 0; i < 2; ++i)
    #pragma unroll
    for (int j = 0; j < 4; ++j) {
      const int col = j * 16 + lrow;                 // d (P) or h (V)
      const float badd = bf2f(bias[col]);
      u16x4 pk4;
      #pragma unroll
      for (int r = 0; r < 4; ++r) {
        float v = acc[i][j][r] + badd;
        if (!isV) v = v > 0.0f ? v + 1.0f : __expf(v);
        pk4[r] = f2bf(v);
      }
      *(u16x4*)&Ttile[col * 72 + wm + i * 16 + quad * 4] = pk4;
    }
  __syncthreads();

  // sT[h][d] = sum_k V[k][h] * P[k][d]  (A' = Vt rows h, B' = Pt rows d, K=64)
  const int wm2 = (wave >> 1) * 32, wn2 = (wave & 1) * 32;
  f32x4 a2[2][2] = {};
  #pragma unroll
  for (int c = 0; c < 2; ++c) {
    bf16x8 av[2], bv[2];
    #pragma unroll
    for (int i = 0; i < 2; ++i)
      av[i] = *(const bf16x8*)&Vt[(wm2 + i * 16 + lrow) * 72 + c * 32 + quad * 8];
    #pragma unroll
    for (int j = 0; j < 2; ++j)
      bv[j] = *(const bf16x8*)&Pt[(wn2 + j * 16 + lrow) * 72 + c * 32 + quad * 8];
    #pragma unroll
    for (int i = 0; i < 2; ++i)
      #pragma unroll
      for (int j = 0; j < 2; ++j)
        a2[i][j] = __builtin_amdgcn_mfma_f32_16x16x32_bf16(av[i], bv[j], a2[i][j], 0, 0, 0);
  }
  u16* sTg = sT + (size_t)x * 4096;
  #pragma unroll
  for (int i = 0; i < 2; ++i)
    #pragma unroll
    for (int j = 0; j < 2; ++j)
      #pragma unroll
      for (int r = 0; r < 4; ++r)
        sTg[(size_t)(wm2 + i * 16 + quad * 4 + r) * 64 + wn2 + j * 16 + lrow] = f2bf(a2[i][j][r]);
  // z[d] = sum_k P[k][d] = row-sum of Pt
  if (t < 64) {
    float zz = 0.f;
    #pragma unroll
    for (int g = 0; g < 8; ++g) {
      u16x8 p = *(const u16x8*)&Pt[t * 72 + g * 8];
      #pragma unroll
      for (int e = 0; e < 8; ++e) zz += bf2f(p[e]);
    }
    z[(size_t)x * 64 + t] = zz;
  }
}

// ---------------- m97-style GEMM: bf16 A[M,K] x Bt[N,K] -> C, global_load_lds ----------------
template<int ACT, bool OF32>
__global__ __launch_bounds__(256) void gemm97_k(
    const u16* __restrict__ A, int lda,
    const u16* __restrict__ Bt, int ldb,
    void* __restrict__ Craw, int ldc,
    const u16* __restrict__ bias, int K)
{
  __shared__ u16 As[128 * 32];   // unpadded: GLDS needs contiguous lane order
  __shared__ u16 Bs[128 * 32];
  const int mt = blockIdx.x * 128, nt = blockIdx.y * 128;
  const int t = threadIdx.x, wave = t >> 6, lane = t & 63;
  const int wm = (wave >> 1) * 64, wn = (wave & 1) * 64;
  const int lrow = lane & 15, quad = lane >> 4;
  f32x4 acc[4][4] = {};

  for (int k0 = 0; k0 < K; k0 += 32) {
    __syncthreads();
    #pragma unroll
    for (int p = 0; p < 2; ++p) {
      const int s = wave * 128 + p * 64 + lane;
      const int r = s >> 2, c = (s & 3) * 8;
      const int lb = (wave * 128 + p * 64) * 8;
      GLDS16(&A[(size_t)(mt + r) * lda + k0 + c], &As[lb]);
      GLDS16(&Bt[(size_t)(nt + r) * ldb + k0 + c], &Bs[lb]);
    }
    __syncthreads();

    bf16x8 av[4], bv[4];
    #pragma unroll
    for (int i = 0; i < 4; ++i) av[i] = *(const bf16x8*)&As[(wm + i * 16 + lrow) * 32 + quad * 8];
    #pragma unroll
    for (int j = 0; j < 4; ++j) bv[j] = *(const bf16x8*)&Bs[(wn + j * 16 + lrow) * 32 + quad * 8];
    #pragma unroll
    for (int i = 0; i < 4; ++i)
      #pragma unroll
      for (int j = 0; j < 4; ++j)
        acc[i][j] = __builtin_amdgcn_mfma_f32_16x16x32_bf16(av[i], bv[j], acc[i][j], 0, 0, 0);
  }

  #pragma unroll
  for (int i = 0; i < 4; ++i) {
    #pragma unroll
    for (int j = 0; j < 4; ++j) {
      const int col = nt + wn + j * 16 + lrow;
      const float badd = bias ? bf2f(bias[col]) : 0.0f;
      #pragma unroll
      for (int r = 0; r < 4; ++r) {
        const int row = mt + wm + i * 16 + quad * 4 + r;
        float v = acc[i][j][r] + badd;
        if constexpr (ACT == 1) v = v > 0.0f ? v + 1.0f : __expf(v);
        if constexpr (OF32) ((float*)Craw)[(size_t)row * ldc + col] = v;
        else                ((u16*)Craw)[(size_t)row * ldc + col] = f2bf(v);
      }
    }
  }
}

// ---------------- a_v = (phi_q @ s) / (phi_q . z + eps), fused qz, in-place ----------------
__global__ __launch_bounds__(256) void attn_av_k(
    u16* __restrict__ phi_q, const u16* __restrict__ sT, const float* __restrict__ zbuf)
{
  __shared__ u16 As[64 * 72];
  __shared__ u16 Bs[64 * 72];
  __shared__ float zv[64];
  __shared__ float zpart[4][64];
  __shared__ float zq[64];
  const int x = blockIdx.x, y = blockIdx.y;
  const int b = y / 12, n = y % 12;
  const int t = threadIdx.x;
  u16* Abase = phi_q + (size_t)b * 512 * 768 + (size_t)x * 64 * 768 + n * 64;
  const u16* Bbase = sT + (size_t)y * 4096;
  if (t < 64) zv[t] = zbuf[(size_t)y * 64 + t];
  #pragma unroll
  for (int p = 0; p < 2; ++p) {
    int v = t + p * 256;
    int r = v >> 3, c = (v & 7) * 8;
    *(u16x8*)&As[r * 72 + c] = *(const u16x8*)&Abase[(size_t)r * 768 + c];
    *(u16x8*)&Bs[r * 72 + c] = *(const u16x8*)&Bbase[r * 64 + c];
  }
  __syncthreads();
  {
    int r = t & 63, seg = t >> 6;
    float s = 0.f;
    #pragma unroll
    for (int j = 0; j < 16; ++j) s += bf2f(As[r * 72 + seg * 16 + j]) * zv[seg * 16 + j];
    zpart[seg][r] = s;
  }
  __syncthreads();
  if (t < 64) {
    float s = zpart[0][t] + zpart[1][t] + zpart[2][t] + zpart[3][t];
    zq[t] = 1.0f / (s + 1e-6f);
  }
  const int wave = t >> 6, lane = t & 63;
  const int wm = (wave >> 1) * 32, wn = (wave & 1) * 32;
  const int lrow = lane & 15, quad = lane >> 4;
  f32x4 acc[2][2] = {};
  #pragma unroll
  for (int c = 0; c < 2; ++c) {
    bf16x8 av[2], bv[2];
    #pragma unroll
    for (int i = 0; i < 2; ++i) av[i] = *(const bf16x8*)&As[(wm + i * 16 + lrow) * 72 + c * 32 + quad * 8];
    #pragma unroll
    for (int j = 0; j < 2; ++j) bv[j] = *(const bf16x8*)&Bs[(wn + j * 16 + lrow) * 72 + c * 32 + quad * 8];
    #pragma unroll
    for (int i = 0; i < 2; ++i)
      #pragma unroll
      for (int j = 0; j < 2; ++j)
        acc[i][j] = __builtin_amdgcn_mfma_f32_16x16x32_bf16(av[i], bv[j], acc[i][j], 0, 0, 0);
  }
  __syncthreads();
  #pragma unroll
  for (int i = 0; i < 2; ++i)
    #pragma unroll
    for (int j = 0; j < 2; ++j) {
      const int col = wn + j * 16 + lrow;
      #pragma unroll
      for (int r = 0; r < 4; ++r) {
        const int row = wm + i * 16 + quad * 4 + r;
        Abase[(size_t)row * 768 + col] = f2bf(acc[i][j][r] * zq[row]);
      }
    }
}

__global__ void tagfill_k(float* out, float val, int n) {
  int i = blockIdx.x * 256 + threadIdx.x;
  if (i < n) out[i] = val;
}

extern "C" void kernel_launch(void* const* d_in, const int* in_sizes, int n_in,
                              void* d_out, int out_size, void* d_ws, size_t ws_size,
                              hipStream_t stream) {
  (void)out_size;
  float* out = (float*)d_out;

  int o;
  if (n_in >= 14 && in_sizes[3] == 1) o = 4;
  else if (n_in == 13) o = 3;
  else { tagfill_k<<<4, 256, 0, stream>>>(out, 77.0f, 1024); return; }
  if (in_sizes[0] != 12582912 || in_sizes[o + 0] != 32768 || in_sizes[o + 2] != 589824) {
    tagfill_k<<<4, 256, 0, stream>>>(out, 88.0f, 1024); return;
  }

  const float* query = (const float*)d_in[0];
  const float* key   = (const float*)d_in[1];
  const float* value = (const float*)d_in[2];
  const float* W_kds = (const float*)d_in[o + 0];
  const float* W_vds = (const float*)d_in[o + 1];
  const float* Wq   = (const float*)d_in[o + 2];
  const float* bq   = (const float*)d_in[o + 3];
  const float* Wk   = (const float*)d_in[o + 4];
  const float* bk   = (const float*)d_in[o + 5];
  const float* Wv   = (const float*)d_in[o + 6];
  const float* bv   = (const float*)d_in[o + 7];
  const float* Wout = (const float*)d_in[o + 8];
  const float* bout = (const float*)d_in[o + 9];

  const size_t NEED = 61478912;
  if (ws_size < NEED) { tagfill_k<<<4, 256, 0, stream>>>(out, 123.0f, 1024); return; }

  char* base = (char*)d_ws;
  u16*   WT     = (u16*)base;                         // 4,718,592
  char*  Breg   = base + 4718592;                     // 25,165,824 region
  u16*   q_bf   = (u16*)Breg;                         // dies after phi_q GEMM
  u16*   sT     = (u16*)Breg;                         // then sT (over q_bf, dead)
  float* zbuf   = (float*)(Breg + 3145728);           // over dead q_bf
  u16*   phi_q  = (u16*)(base + 29884416);            // 25,165,824
  u16*   bias_c = (u16*)(base + 55181312);            // 6,144
  u16*   key_ds = (u16*)(base + 55187456);            // 6,291,456
  u16* a_v = phi_q;
  u16* WqT   = WT;
  u16* WoutT = WT + 3 * 768 * 768;
  u16* bq_c = bias_c, *bout_c = bias_c + 2304;

  // 1. prep (standalone again: merges cost occupancy twice, R2/R3)
  prep_k<<<6732, 256, 0, stream>>>(Wq, Wk, Wv, Wout, query,
                                   bq, bk, bv, bout, WT, q_bf, bias_c);

  // 2. phi_q = elu(q_bf @ Wq + bq) + 1
  gemm97_k<1, false><<<dim3(128, 6), 256, 0, stream>>>(
      q_bf, 768, WqT, 768, phi_q, 768, bq_c, 768);

  // 3. downsample: barrier-free VALU streaming (reads raw fp32 key/value + W direct)
  ds_k<<<dim3(3, 64, 4), 128, 0, stream>>>(W_kds, W_vds, key, value, key_ds);

  // 4. fused phi_k/vals + KV state (sT/zbuf overwrite q_bf — dead after step 2)
  fkv_k<<<384, 256, 0, stream>>>(key_ds, WT, bias_c, sT, zbuf);

  // 5. a_v = (phi_q @ s) * 1/(phi_q.z+eps), fused qz, in-place
  attn_av_k<<<dim3(8, 384), 256, 0, stream>>>(phi_q, sT, zbuf);

  // 6. out = a_v @ Wout + bout (fp32 C)
  gemm97_k<0, true><<<dim3(128, 6), 256, 0, stream>>>(
      a_v, 768, WoutT, 768, out, 768, bout_c, 768);
}

// Round 5
// 307.737 us; speedup vs baseline: 1.2379x; 1.2379x over previous
//
#include <hip/hip_runtime.h>

typedef unsigned short u16;
typedef u16 u16x4 __attribute__((ext_vector_type(4)));
typedef u16 u16x8 __attribute__((ext_vector_type(8)));
typedef __bf16 bf16;
typedef bf16 bf16x8 __attribute__((ext_vector_type(8)));
typedef float f32x4 __attribute__((ext_vector_type(4)));

__device__ __forceinline__ float bf2f(u16 v) {
  union { unsigned u; float f; } x; x.u = ((unsigned)v) << 16; return x.f;
}
__device__ __forceinline__ u16 f2bf(float f) {
  union { float f; unsigned u; } x; x.f = f;
  unsigned u = x.u;
  u += 0x7fffu + ((u >> 16) & 1u);   // RNE
  return (u16)(u >> 16);
}
// hw packed f32->bf16 (RNE), 2 values / instr (no builtin on gfx950, m240)
__device__ __forceinline__ unsigned cvt2bf(float lo, float hi) {
  unsigned r;
  asm("v_cvt_pk_bf16_f32 %0, %1, %2" : "=v"(r) : "v"(lo), "v"(hi));
  return r;
}

// async global->LDS, 16B per lane; LDS base wave-uniform, global source per-lane (m173)
#define GLDS16(g, l) __builtin_amdgcn_global_load_lds( \
    (const __attribute__((address_space(1))) unsigned int*)(const void*)(g), \
    (__attribute__((address_space(3))) unsigned int*)(void*)(l), 16, 0, 0)

// ---------------- prep (compact): 4 weight transposes + Wds cvt + bias cvts ----------------
// query cvt ELIMINATED: phi_q GEMM consumes fp32 query directly (saves 75MB traffic + 20us)
// grid 844: [0,576) transpose4; [576,832) Wds cvt (65536); [832,844) bias (3072)
__global__ __launch_bounds__(256) void prep_k(
    const float* __restrict__ Wq, const float* __restrict__ Wk,
    const float* __restrict__ Wv, const float* __restrict__ Wout,
    const float* __restrict__ wkds, const float* __restrict__ wvds,
    const float* __restrict__ b0, const float* __restrict__ b1,
    const float* __restrict__ b2, const float* __restrict__ b3,
    u16* __restrict__ WT, u16* __restrict__ dstW, u16* __restrict__ dstB)
{
  __shared__ u16 T[64][72];
  const int blk = blockIdx.x;
  const int t = threadIdx.x;
  if (blk < 576) {
    const int bz = blk / 144, rr = blk % 144;
    const int r0 = (rr / 12) * 64, c0 = (rr % 12) * 64;
    const float* W = (bz == 0) ? Wq : (bz == 1) ? Wk : (bz == 2) ? Wv : Wout;
    u16* O = WT + (size_t)bz * 768 * 768;
    #pragma unroll
    for (int p = 0; p < 2; ++p) {
      int v = t + p * 256;
      int r = v / 8, c = (v % 8) * 8;
      f32x4 x0 = *(const f32x4*)&W[(size_t)(r0 + r) * 768 + c0 + c];
      f32x4 x1 = *(const f32x4*)&W[(size_t)(r0 + r) * 768 + c0 + c + 4];
      #pragma unroll
      for (int i = 0; i < 4; ++i) { T[r][c + i] = f2bf(x0[i]); T[r][c + 4 + i] = f2bf(x1[i]); }
    }
    __syncthreads();
    #pragma unroll
    for (int p = 0; p < 2; ++p) {
      int v = t + p * 256;
      int r = v / 8, c = (v % 8) * 8;
      u16x8 tv;
      #pragma unroll
      for (int i = 0; i < 8; ++i) tv[i] = T[c + i][r];
      *(u16x8*)&O[(size_t)(c0 + r) * 768 + r0 + c] = tv;
    }
  } else if (blk < 832) {
    const int i = (blk - 576) * 256 + t;   // 65536
    if (i < 32768) dstW[i] = f2bf(wkds[i]);
    else           dstW[i] = f2bf(wvds[i - 32768]);
  } else {
    const int i = (blk - 832) * 256 + t;   // 3072
    if (i < 3072) {
      int s = i / 768, si = i % 768;
      const float* src = (s == 0) ? b0 : (s == 1) ? b1 : (s == 2) ? b2 : b3;
      dstB[i] = f2bf(src[si]);
    }
  }
}

// ---------------- downsample (R1 proven, 47us): reg-staged, double-buffered LDS ----------
// grid (12, 64): y = pair*32 + b; x = 64-wide d-tile. M=64, N=64, K=512, BK=32.
__global__ __launch_bounds__(256) void ds_k(
    const u16* __restrict__ Wds,      // bf16 [2][64][512]
    const float* __restrict__ key, const float* __restrict__ value,
    u16* __restrict__ key_ds)         // [2][32][64][768] (key_ds ++ val_ds contiguous)
{
  __shared__ u16 Bs[2][64 * 40];     // [buf][n][k], LDSK=40
  const int pair = blockIdx.y >> 5, b = blockIdx.y & 31;
  const float* src = (pair ? value : key) + (size_t)b * 512 * 768;
  const u16* W = Wds + pair * 32768;
  u16* dst = key_ds + (size_t)pair * 1572864 + (size_t)b * 49152;
  const int nt = blockIdx.x * 64;
  const int t = threadIdx.x, wave = t >> 6, lane = t & 63;
  const int wm = (wave >> 1) * 32, wn = (wave & 1) * 32;
  const int lrow = lane & 15, quad = lane >> 4;
  const int bn = t & 63, bk8 = (t >> 6) * 8;
  const float* bcol = src + nt + bn;

  f32x4 acc[2][2] = {};
  float breg[8];
  bf16x8 av[2][2];

  #pragma unroll
  for (int i = 0; i < 8; ++i) breg[i] = bcol[(size_t)(bk8 + i) * 768];
  #pragma unroll
  for (int i = 0; i < 2; ++i)
    av[0][i] = *(const bf16x8*)&W[(size_t)(wm + i * 16 + lrow) * 512 + quad * 8];

  #pragma unroll
  for (int step = 0; step < 16; ++step) {
    const int cur = step & 1, nxt = cur ^ 1;
    u16x8 wv;
    #pragma unroll
    for (int i = 0; i < 8; ++i) wv[i] = f2bf(breg[i]);
    *(u16x8*)&Bs[cur][bn * 40 + bk8] = wv;
    if (step < 15) {
      const int k1 = (step + 1) * 32;
      #pragma unroll
      for (int i = 0; i < 8; ++i) breg[i] = bcol[(size_t)(k1 + bk8 + i) * 768];
      #pragma unroll
      for (int i = 0; i < 2; ++i)
        av[nxt][i] = *(const bf16x8*)&W[(size_t)(wm + i * 16 + lrow) * 512 + k1 + quad * 8];
    }
    __syncthreads();
    bf16x8 bv[2];
    #pragma unroll
    for (int j = 0; j < 2; ++j)
      bv[j] = *(const bf16x8*)&Bs[cur][(wn + j * 16 + lrow) * 40 + quad * 8];
    #pragma unroll
    for (int i = 0; i < 2; ++i)
      #pragma unroll
      for (int j = 0; j < 2; ++j)
        acc[i][j] = __builtin_amdgcn_mfma_f32_16x16x32_bf16(av[cur][i], bv[j], acc[i][j], 0, 0, 0);
  }

  #pragma unroll
  for (int i = 0; i < 2; ++i)
    #pragma unroll
    for (int j = 0; j < 2; ++j) {
      const int col = nt + wn + j * 16 + lrow;
      #pragma unroll
      for (int r = 0; r < 4; ++r) {
        const int row = wm + i * 16 + quad * 4 + r;
        dst[(size_t)row * 768 + col] = f2bf(acc[i][j][r]);
      }
    }
}

// ---------------- phi_q GEMM, fp32 A direct: C = elu(query @ WqT + bq)+1 ----------------
// M=16384 N=768 K=768. A fp32 staged via GLDS with source chunk-swizzle (2-way, free);
// fragments converted f32->bf16 at read via v_cvt_pk_bf16_f32. XCD-chunked block
// swizzle: 6 n-siblings of each A-tile land consecutively on one XCD -> A read once.
__global__ __launch_bounds__(256) void gemmqf_k(
    const float* __restrict__ A, const u16* __restrict__ Bt,
    u16* __restrict__ C, const u16* __restrict__ bias)
{
  __shared__ float As[128 * 32];   // 16KB, chunk-swizzled
  __shared__ u16 Bs[128 * 32];     // 8KB, linear
  const int blk = blockIdx.x;                   // 768 = 128 mt x 6 nt
  const int wg = (blk & 7) * 96 + (blk >> 3);   // bijective XCD chunk (m204)
  const int mt = (wg / 6) * 128, nt = (wg % 6) * 128;
  const int t = threadIdx.x, wave = t >> 6, lane = t & 63;
  const int wm = (wave >> 1) * 64, wn = (wave & 1) * 64;
  const int lrow = lane & 15, quad = lane >> 4;
  f32x4 acc[4][4] = {};

  for (int k0 = 0; k0 < 768; k0 += 32) {
    __syncthreads();
    #pragma unroll
    for (int p = 0; p < 4; ++p) {     // A: 128 rows x 32 f32, 4 GLDS/thread
      const int idx = wave * 256 + p * 64 + lane;
      const int r = idx >> 3, ch = idx & 7;
      const int chs = ch ^ (r & 7);   // source-side swizzle (#21: both-sides pair)
      GLDS16(&A[(size_t)(mt + r) * 768 + k0 + chs * 4], &As[(wave * 256 + p * 64) * 4]);
    }
    #pragma unroll
    for (int p = 0; p < 2; ++p) {     // B: 128 rows x 32 bf16, 2 GLDS/thread
      const int s = wave * 128 + p * 64 + lane;
      const int r = s >> 2, c = (s & 3) * 8;
      GLDS16(&Bt[(size_t)(nt + r) * 768 + k0 + c], &Bs[(wave * 128 + p * 64) * 8]);
    }
    __syncthreads();

    bf16x8 av[4], bv[4];
    #pragma unroll
    for (int i = 0; i < 4; ++i) {
      const int row = wm + i * 16 + lrow;
      f32x4 a0 = *(const f32x4*)&As[row * 32 + ((2 * quad) ^ (row & 7)) * 4];
      f32x4 a1 = *(const f32x4*)&As[row * 32 + ((2 * quad + 1) ^ (row & 7)) * 4];
      union { unsigned w[4]; bf16x8 v; } cv;
      cv.w[0] = cvt2bf(a0[0], a0[1]); cv.w[1] = cvt2bf(a0[2], a0[3]);
      cv.w[2] = cvt2bf(a1[0], a1[1]); cv.w[3] = cvt2bf(a1[2], a1[3]);
      av[i] = cv.v;
    }
    #pragma unroll
    for (int j = 0; j < 4; ++j) bv[j] = *(const bf16x8*)&Bs[(wn + j * 16 + lrow) * 32 + quad * 8];
    #pragma unroll
    for (int i = 0; i < 4; ++i)
      #pragma unroll
      for (int j = 0; j < 4; ++j)
        acc[i][j] = __builtin_amdgcn_mfma_f32_16x16x32_bf16(av[i], bv[j], acc[i][j], 0, 0, 0);
  }

  #pragma unroll
  for (int i = 0; i < 4; ++i) {
    #pragma unroll
    for (int j = 0; j < 4; ++j) {
      const int col = nt + wn + j * 16 + lrow;
      const float badd = bf2f(bias[col]);
      #pragma unroll
      for (int r = 0; r < 4; ++r) {
        const int row = mt + wm + i * 16 + quad * 4 + r;
        float v = acc[i][j][r] + badd;
        v = v > 0.0f ? v + 1.0f : __expf(v);
        C[(size_t)row * 768 + col] = f2bf(v);
      }
    }
  }
}

// ---------------- m97-style GEMM (bf16 A), XCD-chunk-swizzled 1D grid ----------------
template<int ACT, bool OF32>
__global__ __launch_bounds__(256) void gemm97_k(
    const u16* __restrict__ A, int lda,
    const u16* __restrict__ Bt, int ldb,
    void* __restrict__ Craw, int ldc,
    const u16* __restrict__ bias, int K)
{
  __shared__ u16 As[128 * 32];
  __shared__ u16 Bs[128 * 32];
  const int blk = blockIdx.x;                   // 768 = 128 mt x 6 nt
  const int wg = (blk & 7) * 96 + (blk >> 3);
  const int mt = (wg / 6) * 128, nt = (wg % 6) * 128;
  const int t = threadIdx.x, wave = t >> 6, lane = t & 63;
  const int wm = (wave >> 1) * 64, wn = (wave & 1) * 64;
  const int lrow = lane & 15, quad = lane >> 4;
  f32x4 acc[4][4] = {};

  for (int k0 = 0; k0 < K; k0 += 32) {
    __syncthreads();
    #pragma unroll
    for (int p = 0; p < 2; ++p) {
      const int s = wave * 128 + p * 64 + lane;
      const int r = s >> 2, c = (s & 3) * 8;
      const int lb = (wave * 128 + p * 64) * 8;
      GLDS16(&A[(size_t)(mt + r) * lda + k0 + c], &As[lb]);
      GLDS16(&Bt[(size_t)(nt + r) * ldb + k0 + c], &Bs[lb]);
    }
    __syncthreads();

    bf16x8 av[4], bv[4];
    #pragma unroll
    for (int i = 0; i < 4; ++i) av[i] = *(const bf16x8*)&As[(wm + i * 16 + lrow) * 32 + quad * 8];
    #pragma unroll
    for (int j = 0; j < 4; ++j) bv[j] = *(const bf16x8*)&Bs[(wn + j * 16 + lrow) * 32 + quad * 8];
    #pragma unroll
    for (int i = 0; i < 4; ++i)
      #pragma unroll
      for (int j = 0; j < 4; ++j)
        acc[i][j] = __builtin_amdgcn_mfma_f32_16x16x32_bf16(av[i], bv[j], acc[i][j], 0, 0, 0);
  }

  #pragma unroll
  for (int i = 0; i < 4; ++i) {
    #pragma unroll
    for (int j = 0; j < 4; ++j) {
      const int col = nt + wn + j * 16 + lrow;
      const float badd = bias ? bf2f(bias[col]) : 0.0f;
      #pragma unroll
      for (int r = 0; r < 4; ++r) {
        const int row = mt + wm + i * 16 + quad * 4 + r;
        float v = acc[i][j][r] + badd;
        if constexpr (ACT == 1) v = v > 0.0f ? v + 1.0f : __expf(v);
        if constexpr (OF32) ((float*)Craw)[(size_t)row * ldc + col] = v;
        else                ((u16*)Craw)[(size_t)row * ldc + col] = f2bf(v);
      }
    }
  }
}

// ---------------- fused phi_k/vals GEMM + KV-state ----------------
__global__ __launch_bounds__(256) void fkv_k(
    const u16* __restrict__ key_ds,   // [2][32][64][768] bf16
    const u16* __restrict__ WT,       // WkT at +768^2, WvT at +2*768^2
    const u16* __restrict__ bias_c,   // bk at +768, bv at +1536
    u16* __restrict__ sT, float* __restrict__ z)
{
  __shared__ char sm[32768];
  u16* T0 = (u16*)sm;                 // 4 stage tiles [64][64] bf16, chunk-swizzled
  u16* Pt = (u16*)sm;                 // overlay after GEMM: [64][72]
  u16* Vt = (u16*)(sm + 9216);        // [64][72]
  const int x = blockIdx.x;           // b*12 + n
  const int b = x / 12, n = x % 12;
  const int t = threadIdx.x, wave = t >> 6, lane = t & 63;
  const u16* srcs[4] = {
    key_ds + (size_t)b * 49152,
    WT + 589824 + (size_t)n * 49152,
    key_ds + 1572864 + (size_t)b * 49152,
    WT + 2 * 589824 + (size_t)n * 49152 };
  const int grow = lane >> 3;
  const int gchunk = (lane & 7) ^ (grow & 7);
  const int isV = wave & 1;
  const int wm = (wave >> 1) * 32;
  u16* Atile = T0 + (isV ? 2 : 0) * 4096;
  u16* Btile = T0 + (isV ? 3 : 1) * 4096;
  const int lrow = lane & 15, quad = lane >> 4;
  f32x4 acc[2][4] = {};

  for (int k0 = 0; k0 < 768; k0 += 64) {
    const u16* s = srcs[wave];
    u16* dtile = T0 + wave * 4096;
    #pragma unroll
    for (int j = 0; j < 8; ++j) {
      const u16* gsrc = s + (size_t)(j * 8 + grow) * 768 + k0 + gchunk * 8;
      GLDS16(gsrc, (char*)dtile + j * 1024);
    }
    __syncthreads();
    #pragma unroll
    for (int c = 0; c < 2; ++c) {
      bf16x8 av[2], bv[4];
      #pragma unroll
      for (int i = 0; i < 2; ++i) {
        const int row = wm + i * 16 + lrow;
        av[i] = *(const bf16x8*)&Atile[row * 64 + (((c * 4 + quad) ^ (row & 7)) * 8)];
      }
      #pragma unroll
      for (int j = 0; j < 4; ++j) {
        const int row = j * 16 + lrow;
        bv[j] = *(const bf16x8*)&Btile[row * 64 + (((c * 4 + quad) ^ (row & 7)) * 8)];
      }
      #pragma unroll
      for (int i = 0; i < 2; ++i)
        #pragma unroll
        for (int j = 0; j < 4; ++j)
          acc[i][j] = __builtin_amdgcn_mfma_f32_16x16x32_bf16(av[i], bv[j], acc[i][j], 0, 0, 0);
    }
    __syncthreads();
  }

  const u16* bias = bias_c + (isV ? 1536 : 768) + n * 64;
  u16* Ttile = isV ? Vt : Pt;
  #pragma unroll
  for (int i = 0; i < 2; ++i)
    #pragma unroll
    for (int j = 0; j < 4; ++j) {
      const int col = j * 16 + lrow;
      const float badd = bf2f(bias[col]);
      u16x4 pk4;
      #pragma unroll
      for (int r = 0; r < 4; ++r) {
        float v = acc[i][j][r] + badd;
        if (!isV) v = v > 0.0f ? v + 1.0f : __expf(v);
        pk4[r] = f2bf(v);
      }
      *(u16x4*)&Ttile[col * 72 + wm + i * 16 + quad * 4] = pk4;
    }
  __syncthreads();

  const int wm2 = (wave >> 1) * 32, wn2 = (wave & 1) * 32;
  f32x4 a2[2][2] = {};
  #pragma unroll
  for (int c = 0; c < 2; ++c) {
    bf16x8 av[2], bv[2];
    #pragma unroll
    for (int i = 0; i < 2; ++i)
      av[i] = *(const bf16x8*)&Vt[(wm2 + i * 16 + lrow) * 72 + c * 32 + quad * 8];
    #pragma unroll
    for (int j = 0; j < 2; ++j)
      bv[j] = *(const bf16x8*)&Pt[(wn2 + j * 16 + lrow) * 72 + c * 32 + quad * 8];
    #pragma unroll
    for (int i = 0; i < 2; ++i)
      #pragma unroll
      for (int j = 0; j < 2; ++j)
        a2[i][j] = __builtin_amdgcn_mfma_f32_16x16x32_bf16(av[i], bv[j], a2[i][j], 0, 0, 0);
  }
  u16* sTg = sT + (size_t)x * 4096;
  #pragma unroll
  for (int i = 0; i < 2; ++i)
    #pragma unroll
    for (int j = 0; j < 2; ++j)
      #pragma unroll
      for (int r = 0; r < 4; ++r)
        sTg[(size_t)(wm2 + i * 16 + quad * 4 + r) * 64 + wn2 + j * 16 + lrow] = f2bf(a2[i][j][r]);
  if (t < 64) {
    float zz = 0.f;
    #pragma unroll
    for (int g = 0; g < 8; ++g) {
      u16x8 p = *(const u16x8*)&Pt[t * 72 + g * 8];
      #pragma unroll
      for (int e = 0; e < 8; ++e) zz += bf2f(p[e]);
    }
    z[(size_t)x * 64 + t] = zz;
  }
}

// ---------------- a_v = (phi_q @ s) / (phi_q . z + eps), fused qz, in-place ----------------
__global__ __launch_bounds__(256) void attn_av_k(
    u16* __restrict__ phi_q, const u16* __restrict__ sT, const float* __restrict__ zbuf)
{
  __shared__ u16 As[64 * 72];
  __shared__ u16 Bs[64 * 72];
  __shared__ float zv[64];
  __shared__ float zpart[4][64];
  __shared__ float zq[64];
  const int x = blockIdx.x, y = blockIdx.y;
  const int b = y / 12, n = y % 12;
  const int t = threadIdx.x;
  u16* Abase = phi_q + (size_t)b * 512 * 768 + (size_t)x * 64 * 768 + n * 64;
  const u16* Bbase = sT + (size_t)y * 4096;
  if (t < 64) zv[t] = zbuf[(size_t)y * 64 + t];
  #pragma unroll
  for (int p = 0; p < 2; ++p) {
    int v = t + p * 256;
    int r = v >> 3, c = (v & 7) * 8;
    *(u16x8*)&As[r * 72 + c] = *(const u16x8*)&Abase[(size_t)r * 768 + c];
    *(u16x8*)&Bs[r * 72 + c] = *(const u16x8*)&Bbase[r * 64 + c];
  }
  __syncthreads();
  {
    int r = t & 63, seg = t >> 6;
    float s = 0.f;
    #pragma unroll
    for (int j = 0; j < 16; ++j) s += bf2f(As[r * 72 + seg * 16 + j]) * zv[seg * 16 + j];
    zpart[seg][r] = s;
  }
  __syncthreads();
  if (t < 64) {
    float s = zpart[0][t] + zpart[1][t] + zpart[2][t] + zpart[3][t];
    zq[t] = 1.0f / (s + 1e-6f);
  }
  const int wave = t >> 6, lane = t & 63;
  const int wm = (wave >> 1) * 32, wn = (wave & 1) * 32;
  const int lrow = lane & 15, quad = lane >> 4;
  f32x4 acc[2][2] = {};
  #pragma unroll
  for (int c = 0; c < 2; ++c) {
    bf16x8 av[2], bv[2];
    #pragma unroll
    for (int i = 0; i < 2; ++i) av[i] = *(const bf16x8*)&As[(wm + i * 16 + lrow) * 72 + c * 32 + quad * 8];
    #pragma unroll
    for (int j = 0; j < 2; ++j) bv[j] = *(const bf16x8*)&Bs[(wn + j * 16 + lrow) * 72 + c * 32 + quad * 8];
    #pragma unroll
    for (int i = 0; i < 2; ++i)
      #pragma unroll
      for (int j = 0; j < 2; ++j)
        acc[i][j] = __builtin_amdgcn_mfma_f32_16x16x32_bf16(av[i], bv[j], acc[i][j], 0, 0, 0);
  }
  __syncthreads();
  #pragma unroll
  for (int i = 0; i < 2; ++i)
    #pragma unroll
    for (int j = 0; j < 2; ++j) {
      const int col = wn + j * 16 + lrow;
      #pragma unroll
      for (int r = 0; r < 4; ++r) {
        const int row = wm + i * 16 + quad * 4 + r;
        Abase[(size_t)row * 768 + col] = f2bf(acc[i][j][r] * zq[row]);
      }
    }
}

__global__ void tagfill_k(float* out, float val, int n) {
  int i = blockIdx.x * 256 + threadIdx.x;
  if (i < n) out[i] = val;
}

extern "C" void kernel_launch(void* const* d_in, const int* in_sizes, int n_in,
                              void* d_out, int out_size, void* d_ws, size_t ws_size,
                              hipStream_t stream) {
  (void)out_size;
  float* out = (float*)d_out;

  int o;
  if (n_in >= 14 && in_sizes[3] == 1) o = 4;
  else if (n_in == 13) o = 3;
  else { tagfill_k<<<4, 256, 0, stream>>>(out, 77.0f, 1024); return; }
  if (in_sizes[0] != 12582912 || in_sizes[o + 0] != 32768 || in_sizes[o + 2] != 589824) {
    tagfill_k<<<4, 256, 0, stream>>>(out, 88.0f, 1024); return;
  }

  const float* query = (const float*)d_in[0];
  const float* key   = (const float*)d_in[1];
  const float* value = (const float*)d_in[2];
  const float* W_kds = (const float*)d_in[o + 0];
  const float* W_vds = (const float*)d_in[o + 1];
  const float* Wq   = (const float*)d_in[o + 2];
  const float* bq   = (const float*)d_in[o + 3];
  const float* Wk   = (const float*)d_in[o + 4];
  const float* bk   = (const float*)d_in[o + 5];
  const float* Wv   = (const float*)d_in[o + 6];
  const float* bv   = (const float*)d_in[o + 7];
  const float* Wout = (const float*)d_in[o + 8];
  const float* bout = (const float*)d_in[o + 9];

  const size_t NEED = 61478912;
  if (ws_size < NEED) { tagfill_k<<<4, 256, 0, stream>>>(out, 123.0f, 1024); return; }

  char* base = (char*)d_ws;
  u16*   WT     = (u16*)base;                         // 4,718,592
  char*  Breg   = base + 4718592;                     // scratch region
  u16*   sT     = (u16*)Breg;                         // [384][64][64] bf16
  float* zbuf   = (float*)(Breg + 3145728);
  u16*   phi_q  = (u16*)(base + 29884416);            // 25,165,824
  u16*   bias_c = (u16*)(base + 55181312);            // 6,144
  u16*   key_ds = (u16*)(base + 55187456);            // 6,291,456
  u16*   Wds_c  = (u16*)(base + 55050240);            // 131,072
  u16* a_v = phi_q;
  u16* WqT   = WT;
  u16* WoutT = WT + 3 * 768 * 768;
  u16* bq_c = bias_c, *bout_c = bias_c + 2304;

  // 1. prep: W transposes + Wds cvt + bias (no query pass anymore)
  prep_k<<<844, 256, 0, stream>>>(Wq, Wk, Wv, Wout, W_kds, W_vds,
                                  bq, bk, bv, bout, WT, Wds_c, bias_c);

  // 2. phi_q = elu(query @ WqT + bq) + 1  (fp32 A direct, XCD-swizzled)
  gemmqf_k<<<768, 256, 0, stream>>>(query, WqT, phi_q, bq_c);

  // 3. downsample (R1 proven structure)
  ds_k<<<dim3(12, 64), 256, 0, stream>>>(Wds_c, key, value, key_ds);

  // 4. fused phi_k/vals + KV state
  fkv_k<<<384, 256, 0, stream>>>(key_ds, WT, bias_c, sT, zbuf);

  // 5. a_v = (phi_q @ s) * 1/(phi_q.z+eps), fused qz, in-place
  attn_av_k<<<dim3(8, 384), 256, 0, stream>>>(phi_q, sT, zbuf);

  // 6. out = a_v @ Wout + bout (fp32 C, XCD-swizzled)
  gemm97_k<0, true><<<768, 256, 0, stream>>>(
      a_v, 768, WoutT, 768, out, 768, bout_c, 768);
}

// Round 6
// 297.720 us; speedup vs baseline: 1.2795x; 1.0336x over previous
//
#include <hip/hip_runtime.h>

typedef unsigned short u16;
typedef u16 u16x4 __attribute__((ext_vector_type(4)));
typedef u16 u16x8 __attribute__((ext_vector_type(8)));
typedef __bf16 bf16;
typedef bf16 bf16x8 __attribute__((ext_vector_type(8)));
typedef float f32x4 __attribute__((ext_vector_type(4)));

__device__ __forceinline__ float bf2f(u16 v) {
  union { unsigned u; float f; } x; x.u = ((unsigned)v) << 16; return x.f;
}
__device__ __forceinline__ u16 f2bf(float f) {
  union { float f; unsigned u; } x; x.f = f;
  unsigned u = x.u;
  u += 0x7fffu + ((u >> 16) & 1u);   // RNE
  return (u16)(u >> 16);
}
// hw packed f32->bf16 (RNE), 2 values / instr (no builtin on gfx950, m240)
__device__ __forceinline__ unsigned cvt2bf(float lo, float hi) {
  unsigned r;
  asm("v_cvt_pk_bf16_f32 %0, %1, %2" : "=v"(r) : "v"(lo), "v"(hi));
  return r;
}

// async global->LDS, 16B per lane; LDS base wave-uniform, global source per-lane (m173)
#define GLDS16(g, l) __builtin_amdgcn_global_load_lds( \
    (const __attribute__((address_space(1))) unsigned int*)(const void*)(g), \
    (__attribute__((address_space(3))) unsigned int*)(void*)(l), 16, 0, 0)

// ---------------- prep (compact): 4 weight transposes + Wds cvt + bias cvts ----------------
// grid 844: [0,576) transpose4; [576,832) Wds cvt (65536); [832,844) bias (3072)
__global__ __launch_bounds__(256) void prep_k(
    const float* __restrict__ Wq, const float* __restrict__ Wk,
    const float* __restrict__ Wv, const float* __restrict__ Wout,
    const float* __restrict__ wkds, const float* __restrict__ wvds,
    const float* __restrict__ b0, const float* __restrict__ b1,
    const float* __restrict__ b2, const float* __restrict__ b3,
    u16* __restrict__ WT, u16* __restrict__ dstW, u16* __restrict__ dstB)
{
  __shared__ u16 T[64][72];
  const int blk = blockIdx.x;
  const int t = threadIdx.x;
  if (blk < 576) {
    const int bz = blk / 144, rr = blk % 144;
    const int r0 = (rr / 12) * 64, c0 = (rr % 12) * 64;
    const float* W = (bz == 0) ? Wq : (bz == 1) ? Wk : (bz == 2) ? Wv : Wout;
    u16* O = WT + (size_t)bz * 768 * 768;
    #pragma unroll
    for (int p = 0; p < 2; ++p) {
      int v = t + p * 256;
      int r = v / 8, c = (v % 8) * 8;
      f32x4 x0 = *(const f32x4*)&W[(size_t)(r0 + r) * 768 + c0 + c];
      f32x4 x1 = *(const f32x4*)&W[(size_t)(r0 + r) * 768 + c0 + c + 4];
      #pragma unroll
      for (int i = 0; i < 4; ++i) { T[r][c + i] = f2bf(x0[i]); T[r][c + 4 + i] = f2bf(x1[i]); }
    }
    __syncthreads();
    #pragma unroll
    for (int p = 0; p < 2; ++p) {
      int v = t + p * 256;
      int r = v / 8, c = (v % 8) * 8;
      u16x8 tv;
      #pragma unroll
      for (int i = 0; i < 8; ++i) tv[i] = T[c + i][r];
      *(u16x8*)&O[(size_t)(c0 + r) * 768 + r0 + c] = tv;
    }
  } else if (blk < 832) {
    const int i = (blk - 576) * 256 + t;   // 65536
    if (i < 32768) dstW[i] = f2bf(wkds[i]);
    else           dstW[i] = f2bf(wvds[i - 32768]);
  } else {
    const int i = (blk - 832) * 256 + t;   // 3072
    if (i < 3072) {
      int s = i / 768, si = i % 768;
      const float* src = (s == 0) ? b0 : (s == 1) ? b1 : (s == 2) ? b2 : b3;
      dstB[i] = f2bf(src[si]);
    }
  }
}

// ---------------- downsample (R1 proven, 47us): reg-staged, double-buffered LDS ----------
__global__ __launch_bounds__(256) void ds_k(
    const u16* __restrict__ Wds,      // bf16 [2][64][512]
    const float* __restrict__ key, const float* __restrict__ value,
    u16* __restrict__ key_ds)         // [2][32][64][768] (key_ds ++ val_ds contiguous)
{
  __shared__ u16 Bs[2][64 * 40];     // [buf][n][k], LDSK=40
  const int pair = blockIdx.y >> 5, b = blockIdx.y & 31;
  const float* src = (pair ? value : key) + (size_t)b * 512 * 768;
  const u16* W = Wds + pair * 32768;
  u16* dst = key_ds + (size_t)pair * 1572864 + (size_t)b * 49152;
  const int nt = blockIdx.x * 64;
  const int t = threadIdx.x, wave = t >> 6, lane = t & 63;
  const int wm = (wave >> 1) * 32, wn = (wave & 1) * 32;
  const int lrow = lane & 15, quad = lane >> 4;
  const int bn = t & 63, bk8 = (t >> 6) * 8;
  const float* bcol = src + nt + bn;

  f32x4 acc[2][2] = {};
  float breg[8];
  bf16x8 av[2][2];

  #pragma unroll
  for (int i = 0; i < 8; ++i) breg[i] = bcol[(size_t)(bk8 + i) * 768];
  #pragma unroll
  for (int i = 0; i < 2; ++i)
    av[0][i] = *(const bf16x8*)&W[(size_t)(wm + i * 16 + lrow) * 512 + quad * 8];

  #pragma unroll
  for (int step = 0; step < 16; ++step) {
    const int cur = step & 1, nxt = cur ^ 1;
    u16x8 wv;
    #pragma unroll
    for (int i = 0; i < 8; ++i) wv[i] = f2bf(breg[i]);
    *(u16x8*)&Bs[cur][bn * 40 + bk8] = wv;
    if (step < 15) {
      const int k1 = (step + 1) * 32;
      #pragma unroll
      for (int i = 0; i < 8; ++i) breg[i] = bcol[(size_t)(k1 + bk8 + i) * 768];
      #pragma unroll
      for (int i = 0; i < 2; ++i)
        av[nxt][i] = *(const bf16x8*)&W[(size_t)(wm + i * 16 + lrow) * 512 + k1 + quad * 8];
    }
    __syncthreads();
    bf16x8 bv[2];
    #pragma unroll
    for (int j = 0; j < 2; ++j)
      bv[j] = *(const bf16x8*)&Bs[cur][(wn + j * 16 + lrow) * 40 + quad * 8];
    #pragma unroll
    for (int i = 0; i < 2; ++i)
      #pragma unroll
      for (int j = 0; j < 2; ++j)
        acc[i][j] = __builtin_amdgcn_mfma_f32_16x16x32_bf16(av[cur][i], bv[j], acc[i][j], 0, 0, 0);
  }

  #pragma unroll
  for (int i = 0; i < 2; ++i)
    #pragma unroll
    for (int j = 0; j < 2; ++j) {
      const int col = nt + wn + j * 16 + lrow;
      #pragma unroll
      for (int r = 0; r < 4; ++r) {
        const int row = wm + i * 16 + quad * 4 + r;
        dst[(size_t)row * 768 + col] = f2bf(acc[i][j][r]);
      }
    }
}

// ---------------- phi_q GEMM v2: fp32 A direct, BK=64 (12 barrier-pairs, 32 MFMA each) ----
// As: [128][64] f32, 16B-chunk XOR-swizzled (LDS[r][ch] = global[r][ch^(r&15)]) -> 2-way reads
// Bs: [128][64] bf16, chunk-swizzled ch^(r&7) -> 2-way reads
__global__ __launch_bounds__(256) void gemmqf_k(
    const float* __restrict__ A, const u16* __restrict__ Bt,
    u16* __restrict__ C, const u16* __restrict__ bias)
{
  __shared__ float As[128 * 64];   // 32KB
  __shared__ u16 Bs[128 * 64];     // 16KB
  const int blk = blockIdx.x;                   // 768 = 128 mt x 6 nt
  const int wg = (blk & 7) * 96 + (blk >> 3);   // bijective XCD chunk (m204)
  const int mt = (wg / 6) * 128, nt = (wg % 6) * 128;
  const int t = threadIdx.x, wave = t >> 6, lane = t & 63;
  const int wm = (wave >> 1) * 64, wn = (wave & 1) * 64;
  const int lrow = lane & 15, quad = lane >> 4;
  f32x4 acc[4][4] = {};

  for (int k0 = 0; k0 < 768; k0 += 64) {
    __syncthreads();
    #pragma unroll
    for (int p = 0; p < 8; ++p) {     // A: 2048 slots x 16B, 8 GLDS/thread
      const int slot = wave * 512 + p * 64 + lane;
      const int r = slot >> 4, ch = slot & 15;
      const int chs = ch ^ (r & 15);  // source-side swizzle (#21 both-sides pair)
      GLDS16(&A[(size_t)(mt + r) * 768 + k0 + chs * 4], &As[(wave * 512 + p * 64) * 4]);
    }
    #pragma unroll
    for (int p = 0; p < 4; ++p) {     // B: 1024 slots x 16B, 4 GLDS/thread
      const int slot = wave * 256 + p * 64 + lane;
      const int r = slot >> 3, ch = slot & 7;
      const int chs = ch ^ (r & 7);
      GLDS16(&Bt[(size_t)(nt + r) * 768 + k0 + chs * 8], &Bs[(wave * 256 + p * 64) * 8]);
    }
    __syncthreads();

    #pragma unroll
    for (int c = 0; c < 2; ++c) {
      bf16x8 av[4], bv[4];
      #pragma unroll
      for (int i = 0; i < 4; ++i) {
        const int row = wm + i * 16 + lrow;
        const int g0 = c * 8 + 2 * quad;
        f32x4 a0 = *(const f32x4*)&As[row * 64 + ((g0 ^ (row & 15)) * 4)];
        f32x4 a1 = *(const f32x4*)&As[row * 64 + (((g0 + 1) ^ (row & 15)) * 4)];
        union { unsigned w[4]; bf16x8 v; } cv;
        cv.w[0] = cvt2bf(a0[0], a0[1]); cv.w[1] = cvt2bf(a0[2], a0[3]);
        cv.w[2] = cvt2bf(a1[0], a1[1]); cv.w[3] = cvt2bf(a1[2], a1[3]);
        av[i] = cv.v;
      }
      #pragma unroll
      for (int j = 0; j < 4; ++j) {
        const int row = wn + j * 16 + lrow;
        const int g = c * 4 + quad;
        bv[j] = *(const bf16x8*)&Bs[row * 64 + ((g ^ (row & 7)) * 8)];
      }
      #pragma unroll
      for (int i = 0; i < 4; ++i)
        #pragma unroll
        for (int j = 0; j < 4; ++j)
          acc[i][j] = __builtin_amdgcn_mfma_f32_16x16x32_bf16(av[i], bv[j], acc[i][j], 0, 0, 0);
    }
  }

  #pragma unroll
  for (int i = 0; i < 4; ++i) {
    #pragma unroll
    for (int j = 0; j < 4; ++j) {
      const int col = nt + wn + j * 16 + lrow;
      const float badd = bf2f(bias[col]);
      #pragma unroll
      for (int r = 0; r < 4; ++r) {
        const int row = mt + wm + i * 16 + quad * 4 + r;
        float v = acc[i][j][r] + badd;
        v = v > 0.0f ? v + 1.0f : __expf(v);
        C[(size_t)row * 768 + col] = f2bf(v);
      }
    }
  }
}

// ---------------- bf16 GEMM, BK=64, both tiles chunk-swizzled, XCD-chunked grid ----------
template<int ACT, bool OF32>
__global__ __launch_bounds__(256) void gemm64_k(
    const u16* __restrict__ A, int lda,
    const u16* __restrict__ Bt, int ldb,
    void* __restrict__ Craw, int ldc,
    const u16* __restrict__ bias, int K)
{
  __shared__ u16 As[128 * 64];   // 16KB, swizzled ch^(r&7)
  __shared__ u16 Bs[128 * 64];   // 16KB, swizzled
  const int blk = blockIdx.x;                   // 768 = 128 mt x 6 nt
  const int wg = (blk & 7) * 96 + (blk >> 3);
  const int mt = (wg / 6) * 128, nt = (wg % 6) * 128;
  const int t = threadIdx.x, wave = t >> 6, lane = t & 63;
  const int wm = (wave >> 1) * 64, wn = (wave & 1) * 64;
  const int lrow = lane & 15, quad = lane >> 4;
  f32x4 acc[4][4] = {};

  for (int k0 = 0; k0 < K; k0 += 64) {
    __syncthreads();
    #pragma unroll
    for (int p = 0; p < 4; ++p) {
      const int slot = wave * 256 + p * 64 + lane;
      const int r = slot >> 3, ch = slot & 7;
      const int chs = ch ^ (r & 7);
      const int lb = (wave * 256 + p * 64) * 8;
      GLDS16(&A[(size_t)(mt + r) * lda + k0 + chs * 8], &As[lb]);
      GLDS16(&Bt[(size_t)(nt + r) * ldb + k0 + chs * 8], &Bs[lb]);
    }
    __syncthreads();

    #pragma unroll
    for (int c = 0; c < 2; ++c) {
      bf16x8 av[4], bv[4];
      #pragma unroll
      for (int i = 0; i < 4; ++i) {
        const int row = wm + i * 16 + lrow;
        const int g = c * 4 + quad;
        av[i] = *(const bf16x8*)&As[row * 64 + ((g ^ (row & 7)) * 8)];
      }
      #pragma unroll
      for (int j = 0; j < 4; ++j) {
        const int row = wn + j * 16 + lrow;
        const int g = c * 4 + quad;
        bv[j] = *(const bf16x8*)&Bs[row * 64 + ((g ^ (row & 7)) * 8)];
      }
      #pragma unroll
      for (int i = 0; i < 4; ++i)
        #pragma unroll
        for (int j = 0; j < 4; ++j)
          acc[i][j] = __builtin_amdgcn_mfma_f32_16x16x32_bf16(av[i], bv[j], acc[i][j], 0, 0, 0);
    }
  }

  #pragma unroll
  for (int i = 0; i < 4; ++i) {
    #pragma unroll
    for (int j = 0; j < 4; ++j) {
      const int col = nt + wn + j * 16 + lrow;
      const float badd = bias ? bf2f(bias[col]) : 0.0f;
      #pragma unroll
      for (int r = 0; r < 4; ++r) {
        const int row = mt + wm + i * 16 + quad * 4 + r;
        float v = acc[i][j][r] + badd;
        if constexpr (ACT == 1) v = v > 0.0f ? v + 1.0f : __expf(v);
        if constexpr (OF32) ((float*)Craw)[(size_t)row * ldc + col] = v;
        else                ((u16*)Craw)[(size_t)row * ldc + col] = f2bf(v);
      }
    }
  }
}

// ---------------- fused phi_k/vals GEMM + KV-state ----------------
__global__ __launch_bounds__(256) void fkv_k(
    const u16* __restrict__ key_ds,   // [2][32][64][768] bf16
    const u16* __restrict__ WT,       // WkT at +768^2, WvT at +2*768^2
    const u16* __restrict__ bias_c,   // bk at +768, bv at +1536
    u16* __restrict__ sT, float* __restrict__ z)
{
  __shared__ char sm[32768];
  u16* T0 = (u16*)sm;                 // 4 stage tiles [64][64] bf16, chunk-swizzled
  u16* Pt = (u16*)sm;                 // overlay after GEMM: [64][72]
  u16* Vt = (u16*)(sm + 9216);        // [64][72]
  const int x = blockIdx.x;           // b*12 + n
  const int b = x / 12, n = x % 12;
  const int t = threadIdx.x, wave = t >> 6, lane = t & 63;
  const u16* srcs[4] = {
    key_ds + (size_t)b * 49152,
    WT + 589824 + (size_t)n * 49152,
    key_ds + 1572864 + (size_t)b * 49152,
    WT + 2 * 589824 + (size_t)n * 49152 };
  const int grow = lane >> 3;
  const int gchunk = (lane & 7) ^ (grow & 7);
  const int isV = wave & 1;
  const int wm = (wave >> 1) * 32;
  u16* Atile = T0 + (isV ? 2 : 0) * 4096;
  u16* Btile = T0 + (isV ? 3 : 1) * 4096;
  const int lrow = lane & 15, quad = lane >> 4;
  f32x4 acc[2][4] = {};

  for (int k0 = 0; k0 < 768; k0 += 64) {
    const u16* s = srcs[wave];
    u16* dtile = T0 + wave * 4096;
    #pragma unroll
    for (int j = 0; j < 8; ++j) {
      const u16* gsrc = s + (size_t)(j * 8 + grow) * 768 + k0 + gchunk * 8;
      GLDS16(gsrc, (char*)dtile + j * 1024);
    }
    __syncthreads();
    #pragma unroll
    for (int c = 0; c < 2; ++c) {
      bf16x8 av[2], bv[4];
      #pragma unroll
      for (int i = 0; i < 2; ++i) {
        const int row = wm + i * 16 + lrow;
        av[i] = *(const bf16x8*)&Atile[row * 64 + (((c * 4 + quad) ^ (row & 7)) * 8)];
      }
      #pragma unroll
      for (int j = 0; j < 4; ++j) {
        const int row = j * 16 + lrow;
        bv[j] = *(const bf16x8*)&Btile[row * 64 + (((c * 4 + quad) ^ (row & 7)) * 8)];
      }
      #pragma unroll
      for (int i = 0; i < 2; ++i)
        #pragma unroll
        for (int j = 0; j < 4; ++j)
          acc[i][j] = __builtin_amdgcn_mfma_f32_16x16x32_bf16(av[i], bv[j], acc[i][j], 0, 0, 0);
    }
    __syncthreads();
  }

  const u16* bias = bias_c + (isV ? 1536 : 768) + n * 64;
  u16* Ttile = isV ? Vt : Pt;
  #pragma unroll
  for (int i = 0; i < 2; ++i)
    #pragma unroll
    for (int j = 0; j < 4; ++j) {
      const int col = j * 16 + lrow;
      const float badd = bf2f(bias[col]);
      u16x4 pk4;
      #pragma unroll
      for (int r = 0; r < 4; ++r) {
        float v = acc[i][j][r] + badd;
        if (!isV) v = v > 0.0f ? v + 1.0f : __expf(v);
        pk4[r] = f2bf(v);
      }
      *(u16x4*)&Ttile[col * 72 + wm + i * 16 + quad * 4] = pk4;
    }
  __syncthreads();

  const int wm2 = (wave >> 1) * 32, wn2 = (wave & 1) * 32;
  f32x4 a2[2][2] = {};
  #pragma unroll
  for (int c = 0; c < 2; ++c) {
    bf16x8 av[2], bv[2];
    #pragma unroll
    for (int i = 0; i < 2; ++i)
      av[i] = *(const bf16x8*)&Vt[(wm2 + i * 16 + lrow) * 72 + c * 32 + quad * 8];
    #pragma unroll
    for (int j = 0; j < 2; ++j)
      bv[j] = *(const bf16x8*)&Pt[(wn2 + j * 16 + lrow) * 72 + c * 32 + quad * 8];
    #pragma unroll
    for (int i = 0; i < 2; ++i)
      #pragma unroll
      for (int j = 0; j < 2; ++j)
        a2[i][j] = __builtin_amdgcn_mfma_f32_16x16x32_bf16(av[i], bv[j], a2[i][j], 0, 0, 0);
  }
  u16* sTg = sT + (size_t)x * 4096;
  #pragma unroll
  for (int i = 0; i < 2; ++i)
    #pragma unroll
    for (int j = 0; j < 2; ++j)
      #pragma unroll
      for (int r = 0; r < 4; ++r)
        sTg[(size_t)(wm2 + i * 16 + quad * 4 + r) * 64 + wn2 + j * 16 + lrow] = f2bf(a2[i][j][r]);
  if (t < 64) {
    float zz = 0.f;
    #pragma unroll
    for (int g = 0; g < 8; ++g) {
      u16x8 p = *(const u16x8*)&Pt[t * 72 + g * 8];
      #pragma unroll
      for (int e = 0; e < 8; ++e) zz += bf2f(p[e]);
    }
    z[(size_t)x * 64 + t] = zz;
  }
}

// ---------------- a_v = (phi_q @ s) / (phi_q . z + eps), fused qz, in-place ----------------
__global__ __launch_bounds__(256) void attn_av_k(
    u16* __restrict__ phi_q, const u16* __restrict__ sT, const float* __restrict__ zbuf)
{
  __shared__ u16 As[64 * 72];
  __shared__ u16 Bs[64 * 72];
  __shared__ float zv[64];
  __shared__ float zpart[4][64];
  __shared__ float zq[64];
  const int x = blockIdx.x, y = blockIdx.y;
  const int b = y / 12, n = y % 12;
  const int t = threadIdx.x;
  u16* Abase = phi_q + (size_t)b * 512 * 768 + (size_t)x * 64 * 768 + n * 64;
  const u16* Bbase = sT + (size_t)y * 4096;
  if (t < 64) zv[t] = zbuf[(size_t)y * 64 + t];
  #pragma unroll
  for (int p = 0; p < 2; ++p) {
    int v = t + p * 256;
    int r = v >> 3, c = (v & 7) * 8;
    *(u16x8*)&As[r * 72 + c] = *(const u16x8*)&Abase[(size_t)r * 768 + c];
    *(u16x8*)&Bs[r * 72 + c] = *(const u16x8*)&Bbase[r * 64 + c];
  }
  __syncthreads();
  {
    int r = t & 63, seg = t >> 6;
    float s = 0.f;
    #pragma unroll
    for (int j = 0; j < 16; ++j) s += bf2f(As[r * 72 + seg * 16 + j]) * zv[seg * 16 + j];
    zpart[seg][r] = s;
  }
  __syncthreads();
  if (t < 64) {
    float s = zpart[0][t] + zpart[1][t] + zpart[2][t] + zpart[3][t];
    zq[t] = 1.0f / (s + 1e-6f);
  }
  const int wave = t >> 6, lane = t & 63;
  const int wm = (wave >> 1) * 32, wn = (wave & 1) * 32;
  const int lrow = lane & 15, quad = lane >> 4;
  f32x4 acc[2][2] = {};
  #pragma unroll
  for (int c = 0; c < 2; ++c) {
    bf16x8 av[2], bv[2];
    #pragma unroll
    for (int i = 0; i < 2; ++i) av[i] = *(const bf16x8*)&As[(wm + i * 16 + lrow) * 72 + c * 32 + quad * 8];
    #pragma unroll
    for (int j = 0; j < 2; ++j) bv[j] = *(const bf16x8*)&Bs[(wn + j * 16 + lrow) * 72 + c * 32 + quad * 8];
    #pragma unroll
    for (int i = 0; i < 2; ++i)
      #pragma unroll
      for (int j = 0; j < 2; ++j)
        acc[i][j] = __builtin_amdgcn_mfma_f32_16x16x32_bf16(av[i], bv[j], acc[i][j], 0, 0, 0);
  }
  __syncthreads();
  #pragma unroll
  for (int i = 0; i < 2; ++i)
    #pragma unroll
    for (int j = 0; j < 2; ++j) {
      const int col = wn + j * 16 + lrow;
      #pragma unroll
      for (int r = 0; r < 4; ++r) {
        const int row = wm + i * 16 + quad * 4 + r;
        Abase[(size_t)row * 768 + col] = f2bf(acc[i][j][r] * zq[row]);
      }
    }
}

__global__ void tagfill_k(float* out, float val, int n) {
  int i = blockIdx.x * 256 + threadIdx.x;
  if (i < n) out[i] = val;
}

extern "C" void kernel_launch(void* const* d_in, const int* in_sizes, int n_in,
                              void* d_out, int out_size, void* d_ws, size_t ws_size,
                              hipStream_t stream) {
  (void)out_size;
  float* out = (float*)d_out;

  int o;
  if (n_in >= 14 && in_sizes[3] == 1) o = 4;
  else if (n_in == 13) o = 3;
  else { tagfill_k<<<4, 256, 0, stream>>>(out, 77.0f, 1024); return; }
  if (in_sizes[0] != 12582912 || in_sizes[o + 0] != 32768 || in_sizes[o + 2] != 589824) {
    tagfill_k<<<4, 256, 0, stream>>>(out, 88.0f, 1024); return;
  }

  const float* query = (const float*)d_in[0];
  const float* key   = (const float*)d_in[1];
  const float* value = (const float*)d_in[2];
  const float* W_kds = (const float*)d_in[o + 0];
  const float* W_vds = (const float*)d_in[o + 1];
  const float* Wq   = (const float*)d_in[o + 2];
  const float* bq   = (const float*)d_in[o + 3];
  const float* Wk   = (const float*)d_in[o + 4];
  const float* bk   = (const float*)d_in[o + 5];
  const float* Wv   = (const float*)d_in[o + 6];
  const float* bv   = (const float*)d_in[o + 7];
  const float* Wout = (const float*)d_in[o + 8];
  const float* bout = (const float*)d_in[o + 9];

  const size_t NEED = 61478912;
  if (ws_size < NEED) { tagfill_k<<<4, 256, 0, stream>>>(out, 123.0f, 1024); return; }

  char* base = (char*)d_ws;
  u16*   WT     = (u16*)base;                         // 4,718,592
  char*  Breg   = base + 4718592;                     // scratch region
  u16*   sT     = (u16*)Breg;                         // [384][64][64] bf16
  float* zbuf   = (float*)(Breg + 3145728);
  u16*   phi_q  = (u16*)(base + 29884416);            // 25,165,824
  u16*   bias_c = (u16*)(base + 55181312);            // 6,144
  u16*   key_ds = (u16*)(base + 55187456);            // 6,291,456
  u16*   Wds_c  = (u16*)(base + 55050240);            // 131,072
  u16* a_v = phi_q;
  u16* WqT   = WT;
  u16* WoutT = WT + 3 * 768 * 768;
  u16* bq_c = bias_c, *bout_c = bias_c + 2304;

  // 1. prep: W transposes + Wds cvt + bias
  prep_k<<<844, 256, 0, stream>>>(Wq, Wk, Wv, Wout, W_kds, W_vds,
                                  bq, bk, bv, bout, WT, Wds_c, bias_c);

  // 2. phi_q = elu(query @ WqT + bq) + 1  (fp32 A direct, BK=64, XCD-swizzled)
  gemmqf_k<<<768, 256, 0, stream>>>(query, WqT, phi_q, bq_c);

  // 3. downsample (R1 proven structure)
  ds_k<<<dim3(12, 64), 256, 0, stream>>>(Wds_c, key, value, key_ds);

  // 4. fused phi_k/vals + KV state
  fkv_k<<<384, 256, 0, stream>>>(key_ds, WT, bias_c, sT, zbuf);

  // 5. a_v = (phi_q @ s) * 1/(phi_q.z+eps), fused qz, in-place
  attn_av_k<<<dim3(8, 384), 256, 0, stream>>>(phi_q, sT, zbuf);

  // 6. out = a_v @ Wout + bout (fp32 C, BK=64, XCD-swizzled)
  gemm64_k<0, true><<<768, 256, 0, stream>>>(
      a_v, 768, WoutT, 768, out, 768, bout_c, 768);
}